// Round 8
// baseline (617.331 us; speedup 1.0000x reference)
//
#include <hip/hip_runtime.h>

#define DECAYF 0.999f
#define GAINF  0.001f
#define EPSF   1e-6f

// Problem sizes (compile-time): B=512, D=64 dim_codes, K=1024 book, E=64 embed
// out layout: cw[512*4096] | one_hot[512*64*1024] | new_cb[64*1024*64] | new_ema[64*1024]
// d_ws deliberately unused.

#define NB 512
#define ND 64
#define NK 1024
#define NE 64

// ---------------- pre-init: ncb = cb*DECAY ; nema = ema*DECAY ----------------
__global__ void k_pre(const float* __restrict__ cb, const float* __restrict__ ema,
                      float* __restrict__ ncb, float* __restrict__ nema) {
    int i = blockIdx.x * blockDim.x + threadIdx.x;   // 1,064,960 float4s total
    if (i < 1048576) {
        float4 v = ((const float4*)cb)[i];
        v.x *= DECAYF; v.y *= DECAYF; v.z *= DECAYF; v.w *= DECAYF;
        ((float4*)ncb)[i] = v;
    } else {
        int j = i - 1048576;
        float4 v = ((const float4*)ema)[j];
        v.x *= DECAYF; v.y *= DECAYF; v.z *= DECAYF; v.w *= DECAYF;
        ((float4*)nema)[j] = v;
    }
}

// ---------------- fused: hbsq -> argmin -> one_hot + cw + scatter + ema ----------------
// ROUND-7 CHANGE: grid (64 d, 16 bq) with 32 b-rows per block -> 1024 blocks =
// 4 blocks/CU = 32 waves/CU (round-6 was 2 blocks/CU, Occupancy 42%, VALUBusy 32%:
// the scan was stall-bound on L2 latency with only 4 waves/SIMD to hide it).
// __launch_bounds__(512,8) pins VGPR<=64 so 8 waves/SIMD is guaranteed.
// d on grid-x keeps the d%8 XCD affinity (round-5: FETCH 143->20 MB).
// block 512 = 8 waves; wave w scans k-range [w*128, w*128+128) for all 32 b.
// Lane = 32 b x 2 e-halves; x half-row (8 f4 = 32 VGPR) in registers;
// half-dots combined with one shfl_xor(32) (bit-identical on both halves).
__global__ __launch_bounds__(512, 8) void k_fused(
        const float* __restrict__ x, const float* __restrict__ cb,
        const float* __restrict__ ema,
        float* __restrict__ cw, float* __restrict__ oh,
        float* __restrict__ ncb, float* __restrict__ nema) {
    const int d    = blockIdx.x;
    const int bq   = blockIdx.y;        // b-chunk 0..15 (32 rows each)
    const int t    = threadIdx.x;
    const int lane = t & 63;
    const int w    = t >> 6;            // wave 0..7 = k-eighth
    const int h    = lane >> 5;         // e-half 0/1
    const int bb   = lane & 31;         // b within chunk

    __shared__ float s_hbsq[NK];        // 0.5*sum(c^2): dist' = hbsq - dot
    __shared__ float s_best[8][32];
    __shared__ int   s_idx[8][32];
    __shared__ int   s_kf[32];
    __shared__ int   s_cnt[NK];

    s_cnt[t] = 0; s_cnt[t + 512] = 0;

    // phase a: half-b_sq for this d (cooperative, 2 rows/thread)
    const float* cbd = cb + (size_t)d * (NK * NE);
    for (int kk = t; kk < NK; kk += 512) {
        const float4* c4a = (const float4*)(cbd + (size_t)kk * NE);
        float a0 = 0.f, a1 = 0.f, a2 = 0.f, a3 = 0.f;
#pragma unroll
        for (int e4 = 0; e4 < 16; ++e4) {
            float4 v = c4a[e4];
            a0 = fmaf(v.x, v.x, a0); a1 = fmaf(v.y, v.y, a1);
            a2 = fmaf(v.z, v.z, a2); a3 = fmaf(v.w, v.w, a3);
        }
        s_hbsq[kk] = 0.5f * ((a0 + a1) + (a2 + a3));
    }
    __syncthreads();

    // phase b: scan 128 codes; x half-row (32 floats) in registers.
    // argmin(dist) == argmin(hbsq - dot)  (x_sq const shift, x2 positive scale)
    const int b = bq * 32 + bb;
    float4 xr[8];
    const float4* xp4 = (const float4*)(x + (size_t)b * (ND * NE) + d * NE + h * 32);
#pragma unroll
    for (int e4 = 0; e4 < 8; ++e4) xr[e4] = xp4[e4];

    const float4* c4   = (const float4*)(cbd + (size_t)(w * 128) * NE + h * 32);
    const float*  bsqw = s_hbsq + w * 128;
    float best  = 3.4e38f;
    int   bestk = w * 128;
    for (int k = 0; k < 128; ++k) {
        float a0 = 0.f, a1 = 0.f, a2 = 0.f, a3 = 0.f;
#pragma unroll
        for (int e4 = 0; e4 < 8; ++e4) {
            float4 v = c4[e4];                   // half-wave-uniform addr -> broadcast
            a0 = fmaf(v.x, xr[e4].x, a0);
            a1 = fmaf(v.y, xr[e4].y, a1);
            a2 = fmaf(v.z, xr[e4].z, a2);
            a3 = fmaf(v.w, xr[e4].w, a3);
        }
        c4 += 16;                                // next code row (64 floats)
        float half = (a0 + a1) + (a2 + a3);
        float dot  = half + __shfl_xor(half, 32, 64);   // commutative: bit-identical
        float dist = bsqw[k] - dot;
        if (dist < best) { best = dist; bestk = w * 128 + k; }  // strict <: first idx wins
    }
    if (h == 0) { s_best[w][bb] = best; s_idx[w][bb] = bestk; }
    __syncthreads();

    // phase c: per-b reduce over the 8 ascending k-eighths (strict < keeps earliest)
    if (t < 32) {
        float bv = s_best[0][t];
        int   bk = s_idx[0][t];
#pragma unroll
        for (int j = 1; j < 8; ++j) {
            float ob = s_best[j][t];
            if (ob < bv) { bv = ob; bk = s_idx[j][t]; }
        }
        s_kf[t] = bk;
        atomicAdd(&s_cnt[bk], 1);    // LDS histogram
    }
    __syncthreads();

    // phase d: one-hot rows. Wave w owns rows w*4..w*4+3; 4KB contiguous per row.
    for (int rr = 0; rr < 4; ++rr) {
        int r  = w * 4 + rr;
        int kk = s_kf[r];
        float* orow = oh + (size_t)(bq * 32 + r) * (ND * NK) + d * NK;
#pragma unroll
        for (int j = 0; j < 4; ++j) {
            int k0 = j * 256 + lane * 4;
            float4 o;
            o.x = (k0     == kk) ? 1.f : 0.f;
            o.y = (k0 + 1 == kk) ? 1.f : 0.f;
            o.z = (k0 + 2 == kk) ? 1.f : 0.f;
            o.w = (k0 + 3 == kk) ? 1.f : 0.f;
            *(float4*)(orow + k0) = o;
        }
    }

    // phase e+f: cw rows (exact reference arithmetic x+(c-x)) + scatter into ncb
    for (int rr = 0; rr < 4; ++rr) {
        int r  = w * 4 + rr;
        int kk = s_kf[r];
        int br = bq * 32 + r;
        float xv = x[(size_t)br * (ND * NE) + d * NE + lane];
        float cv = cbd[(size_t)kk * NE + lane];
        cw[(size_t)br * (ND * NE) + d * NE + lane] = xv + (cv - xv);
        float scale = GAINF / (ema[d * NK + kk] + EPSF);
        atomicAdd(&ncb[(size_t)d * (NK * NE) + (size_t)kk * NE + lane], scale * xv);
    }

    // phase g: flush histogram into nema (<= 16 blocks collide per bin)
    for (int kk = t; kk < NK; kk += 512) {
        int c = s_cnt[kk];
        if (c) atomicAdd(&nema[d * NK + kk], GAINF * (float)c);
    }
}

extern "C" void kernel_launch(void* const* d_in, const int* in_sizes, int n_in,
                              void* d_out, int out_size, void* d_ws, size_t ws_size,
                              hipStream_t stream) {
    const float* x   = (const float*)d_in[0];   // [512,4096]
    const float* cb  = (const float*)d_in[1];   // [64,1024,64]
    const float* ema = (const float*)d_in[2];   // [64,1024]

    float* out  = (float*)d_out;
    float* cw   = out;                          // 2,097,152
    float* oh   = out + 2097152;                // 33,554,432
    float* ncb  = out + 2097152 + 33554432;     // 4,194,304
    float* nema = ncb + 4194304;                // 65,536

    k_pre<<<4160, 256, 0, stream>>>(cb, ema, ncb, nema);

    dim3 g_fused(64, 16);                       // d on x -> XCD-aligned codebook reuse
    k_fused<<<g_fused, 512, 0, stream>>>(x, cb, ema, cw, oh, ncb, nema);
}

// Round 9
// 430.994 us; speedup vs baseline: 1.4323x; 1.4323x over previous
//
#include <hip/hip_runtime.h>

#define DECAYF 0.999f
#define GAINF  0.001f
#define EPSF   1e-6f

// Problem sizes (compile-time): B=512, D=64 dim_codes, K=1024 book, E=64 embed
// out layout: cw[512*4096] | one_hot[512*64*1024] | new_cb[64*1024*64] | new_ema[64*1024]
// d_ws deliberately unused.

#define NB 512
#define ND 64
#define NK 1024
#define NE 64

// ---------------- pre-init: ncb = cb*DECAY ; nema = ema*DECAY ----------------
__global__ void k_pre(const float* __restrict__ cb, const float* __restrict__ ema,
                      float* __restrict__ ncb, float* __restrict__ nema) {
    int i = blockIdx.x * blockDim.x + threadIdx.x;   // 1,064,960 float4s total
    if (i < 1048576) {
        float4 v = ((const float4*)cb)[i];
        v.x *= DECAYF; v.y *= DECAYF; v.z *= DECAYF; v.w *= DECAYF;
        ((float4*)ncb)[i] = v;
    } else {
        int j = i - 1048576;
        float4 v = ((const float4*)ema)[j];
        v.x *= DECAYF; v.y *= DECAYF; v.z *= DECAYF; v.w *= DECAYF;
        ((float4*)nema)[j] = v;
    }
}

// ---------------- fused: hbsq -> argmin -> one_hot + cw + scatter + ema ----------------
// ROUND-9: round-8 geometry (grid 64x16, 1024 blocks -> 4 blocks/CU = 32 waves/CU)
// but PLAIN __launch_bounds__(512): round-8's (512,8) pin clamped VGPR to 32 and
// spilled xr to scratch (FETCH 23->90MB, WRITE 148->175MB, VALUBusy 20%, 496us).
// Round-6 proved this exact inner loop compiles to 48 VGPR unpinned, and 48<=64
// keeps the 8-waves/SIMD hardware tier available -- the grid now supplies them.
// d on grid-x keeps the d%8 XCD affinity (round-5: FETCH 143->20 MB).
// block 512 = 8 waves; wave w scans k-range [w*128, w*128+128) for all 32 b.
// Lane = 32 b x 2 e-halves; x half-row (8 f4 = 32 VGPR) in registers;
// half-dots combined with one shfl_xor(32) (bit-identical on both halves).
__global__ __launch_bounds__(512) void k_fused(
        const float* __restrict__ x, const float* __restrict__ cb,
        const float* __restrict__ ema,
        float* __restrict__ cw, float* __restrict__ oh,
        float* __restrict__ ncb, float* __restrict__ nema) {
    const int d    = blockIdx.x;
    const int bq   = blockIdx.y;        // b-chunk 0..15 (32 rows each)
    const int t    = threadIdx.x;
    const int lane = t & 63;
    const int w    = t >> 6;            // wave 0..7 = k-eighth
    const int h    = lane >> 5;         // e-half 0/1
    const int bb   = lane & 31;         // b within chunk

    __shared__ float s_hbsq[NK];        // 0.5*sum(c^2): dist' = hbsq - dot
    __shared__ float s_best[8][32];
    __shared__ int   s_idx[8][32];
    __shared__ int   s_kf[32];
    __shared__ int   s_cnt[NK];

    s_cnt[t] = 0; s_cnt[t + 512] = 0;

    // phase a: half-b_sq for this d (cooperative, 2 rows/thread)
    const float* cbd = cb + (size_t)d * (NK * NE);
    for (int kk = t; kk < NK; kk += 512) {
        const float4* c4a = (const float4*)(cbd + (size_t)kk * NE);
        float a0 = 0.f, a1 = 0.f, a2 = 0.f, a3 = 0.f;
#pragma unroll
        for (int e4 = 0; e4 < 16; ++e4) {
            float4 v = c4a[e4];
            a0 = fmaf(v.x, v.x, a0); a1 = fmaf(v.y, v.y, a1);
            a2 = fmaf(v.z, v.z, a2); a3 = fmaf(v.w, v.w, a3);
        }
        s_hbsq[kk] = 0.5f * ((a0 + a1) + (a2 + a3));
    }
    __syncthreads();

    // phase b: scan 128 codes; x half-row (32 floats) in registers.
    // argmin(dist) == argmin(hbsq - dot)  (x_sq const shift, x2 positive scale)
    const int b = bq * 32 + bb;
    float4 xr[8];
    const float4* xp4 = (const float4*)(x + (size_t)b * (ND * NE) + d * NE + h * 32);
#pragma unroll
    for (int e4 = 0; e4 < 8; ++e4) xr[e4] = xp4[e4];

    const float4* c4   = (const float4*)(cbd + (size_t)(w * 128) * NE + h * 32);
    const float*  bsqw = s_hbsq + w * 128;
    float best  = 3.4e38f;
    int   bestk = w * 128;
    for (int k = 0; k < 128; ++k) {
        float a0 = 0.f, a1 = 0.f, a2 = 0.f, a3 = 0.f;
#pragma unroll
        for (int e4 = 0; e4 < 8; ++e4) {
            float4 v = c4[e4];                   // half-wave-uniform addr -> broadcast
            a0 = fmaf(v.x, xr[e4].x, a0);
            a1 = fmaf(v.y, xr[e4].y, a1);
            a2 = fmaf(v.z, xr[e4].z, a2);
            a3 = fmaf(v.w, xr[e4].w, a3);
        }
        c4 += 16;                                // next code row (64 floats)
        float half = (a0 + a1) + (a2 + a3);
        float dot  = half + __shfl_xor(half, 32, 64);   // commutative: bit-identical
        float dist = bsqw[k] - dot;
        if (dist < best) { best = dist; bestk = w * 128 + k; }  // strict <: first idx wins
    }
    if (h == 0) { s_best[w][bb] = best; s_idx[w][bb] = bestk; }
    __syncthreads();

    // phase c: per-b reduce over the 8 ascending k-eighths (strict < keeps earliest)
    if (t < 32) {
        float bv = s_best[0][t];
        int   bk = s_idx[0][t];
#pragma unroll
        for (int j = 1; j < 8; ++j) {
            float ob = s_best[j][t];
            if (ob < bv) { bv = ob; bk = s_idx[j][t]; }
        }
        s_kf[t] = bk;
        atomicAdd(&s_cnt[bk], 1);    // LDS histogram
    }
    __syncthreads();

    // phase d: one-hot rows. Wave w owns rows w*4..w*4+3; 4KB contiguous per row.
    for (int rr = 0; rr < 4; ++rr) {
        int r  = w * 4 + rr;
        int kk = s_kf[r];
        float* orow = oh + (size_t)(bq * 32 + r) * (ND * NK) + d * NK;
#pragma unroll
        for (int j = 0; j < 4; ++j) {
            int k0 = j * 256 + lane * 4;
            float4 o;
            o.x = (k0     == kk) ? 1.f : 0.f;
            o.y = (k0 + 1 == kk) ? 1.f : 0.f;
            o.z = (k0 + 2 == kk) ? 1.f : 0.f;
            o.w = (k0 + 3 == kk) ? 1.f : 0.f;
            *(float4*)(orow + k0) = o;
        }
    }

    // phase e+f: cw rows (exact reference arithmetic x+(c-x)) + scatter into ncb
    for (int rr = 0; rr < 4; ++rr) {
        int r  = w * 4 + rr;
        int kk = s_kf[r];
        int br = bq * 32 + r;
        float xv = x[(size_t)br * (ND * NE) + d * NE + lane];
        float cv = cbd[(size_t)kk * NE + lane];
        cw[(size_t)br * (ND * NE) + d * NE + lane] = xv + (cv - xv);
        float scale = GAINF / (ema[d * NK + kk] + EPSF);
        atomicAdd(&ncb[(size_t)d * (NK * NE) + (size_t)kk * NE + lane], scale * xv);
    }

    // phase g: flush histogram into nema (<= 16 blocks collide per bin)
    for (int kk = t; kk < NK; kk += 512) {
        int c = s_cnt[kk];
        if (c) atomicAdd(&nema[d * NK + kk], GAINF * (float)c);
    }
}

extern "C" void kernel_launch(void* const* d_in, const int* in_sizes, int n_in,
                              void* d_out, int out_size, void* d_ws, size_t ws_size,
                              hipStream_t stream) {
    const float* x   = (const float*)d_in[0];   // [512,4096]
    const float* cb  = (const float*)d_in[1];   // [64,1024,64]
    const float* ema = (const float*)d_in[2];   // [64,1024]

    float* out  = (float*)d_out;
    float* cw   = out;                          // 2,097,152
    float* oh   = out + 2097152;                // 33,554,432
    float* ncb  = out + 2097152 + 33554432;     // 4,194,304
    float* nema = ncb + 4194304;                // 65,536

    k_pre<<<4160, 256, 0, stream>>>(cb, ema, ncb, nema);

    dim3 g_fused(64, 16);                       // d on x -> XCD-aligned codebook reuse
    k_fused<<<g_fused, 512, 0, stream>>>(x, cb, ema, cw, oh, ncb, nema);
}

// Round 10
// 264.892 us; speedup vs baseline: 2.3305x; 1.6271x over previous
//
#include <hip/hip_runtime.h>

#define DECAYF 0.999f
#define GAINF  0.001f
#define EPSF   1e-6f

// Problem sizes (compile-time): B=512, D=64 dim_codes, K=1024 book, E=64 embed
// out layout: cw[512*4096] | one_hot[512*64*1024] | new_cb[64*1024*64] | new_ema[64*1024]
// d_ws deliberately unused.

#define NB 512
#define ND 64
#define NK 1024
#define NE 64

// ---------------- pre-init: ncb = cb*DECAY ; nema = ema*DECAY ----------------
__global__ void k_pre(const float* __restrict__ cb, const float* __restrict__ ema,
                      float* __restrict__ ncb, float* __restrict__ nema) {
    int i = blockIdx.x * blockDim.x + threadIdx.x;   // 1,064,960 float4s total
    if (i < 1048576) {
        float4 v = ((const float4*)cb)[i];
        v.x *= DECAYF; v.y *= DECAYF; v.z *= DECAYF; v.w *= DECAYF;
        ((float4*)ncb)[i] = v;
    } else {
        int j = i - 1048576;
        float4 v = ((const float4*)ema)[j];
        v.x *= DECAYF; v.y *= DECAYF; v.z *= DECAYF; v.w *= DECAYF;
        ((float4*)nema)[j] = v;
    }
}

// ---------------- fused: hbsq -> argmin -> one_hot + cw + scatter + ema ----------------
// ROUND-10 RESTRUCTURE: rounds 6 vs 9 proved the scan is bound by a shared per-CU
// resource, not per-wave latency (2x blocks -> identical 302us / VALUBusy 32%).
// Model: per-lane vector loads of the codebook cost ~16 TA-cycles per wave64 load
// even on broadcast -> 8 loads/iter x 8192 waves x 128 iters / 256 CU ~ 220us. Fix:
// make the codebook stream WAVE-UNIFORM so it rides the SCALAR path (s_load, no TA):
//   lane = b (64 b per wave), e fully unrolled, k sequential per wave.
//   dist = hbsq[k] - dot is lane-local: no shfl in the loop at all.
// x-row (64 f32 = 64 VGPR) per lane; __launch_bounds__(512,4) caps VGPR at 128
// (r8's (512,8) capped at 64 -> scratch spill disaster; r5 default stuck at 60).
// grid (64 d, 8 bq): d%8 XCD affinity (r5: FETCH 143->20MB). 512 thr = 8 k-eighth waves.
__global__ __launch_bounds__(512, 4) void k_fused(
        const float* __restrict__ x, const float* __restrict__ cb,
        const float* __restrict__ ema,
        float* __restrict__ cw, float* __restrict__ oh,
        float* __restrict__ ncb, float* __restrict__ nema) {
    const int d    = blockIdx.x;
    const int bq   = blockIdx.y;        // b-chunk 0..7 (64 rows each)
    const int t    = threadIdx.x;
    const int lane = t & 63;            // b within chunk
    const int w    = __builtin_amdgcn_readfirstlane(t >> 6);  // wave 0..7 = k-eighth (SGPR)

    __shared__ float s_hbsq[NK];        // 0.5*sum(c^2): dist' = hbsq - dot
    __shared__ float s_best[8][64];
    __shared__ int   s_idx[8][64];
    __shared__ int   s_kf[64];
    __shared__ int   s_cnt[NK];

    s_cnt[t] = 0; s_cnt[t + 512] = 0;

    // phase a: half-b_sq for this d (cooperative, 2 rows/thread, coalesced f4 stream)
    const float* cbd = cb + (size_t)d * (NK * NE);
    for (int kk = t; kk < NK; kk += 512) {
        const float4* c4a = (const float4*)(cbd + (size_t)kk * NE);
        float a0 = 0.f, a1 = 0.f, a2 = 0.f, a3 = 0.f;
#pragma unroll
        for (int e4 = 0; e4 < 16; ++e4) {
            float4 v = c4a[e4];
            a0 = fmaf(v.x, v.x, a0); a1 = fmaf(v.y, v.y, a1);
            a2 = fmaf(v.z, v.z, a2); a3 = fmaf(v.w, v.w, a3);
        }
        s_hbsq[kk] = 0.5f * ((a0 + a1) + (a2 + a3));
    }
    __syncthreads();

    // phase b: wave w scans k in [w*128, w*128+128) for 64 b's (lane=b).
    // x row (64 floats) in VGPRs, loaded once; codebook row via wave-uniform
    // scalar loads (no vector-memory traffic in the loop).
    // argmin(dist) == argmin(hbsq - dot)  (x_sq const shift, x2 positive scale)
    const int b = bq * 64 + lane;
    float4 xr[16];
    const float4* xp4 = (const float4*)(x + (size_t)b * (ND * NE) + d * NE);
#pragma unroll
    for (int e4 = 0; e4 < 16; ++e4) xr[e4] = xp4[e4];

    const float* crow = cbd + (size_t)(w * 128) * NE;   // wave-uniform pointer
    const float* bsqw = s_hbsq + w * 128;
    float best  = 3.4e38f;
    int   bestk = w * 128;
    for (int k = 0; k < 128; ++k) {
        float a0 = 0.f, a1 = 0.f, a2 = 0.f, a3 = 0.f;
#pragma unroll
        for (int e = 0; e < 64; e += 4) {
            a0 = fmaf(crow[e],     xr[e >> 2].x, a0);   // s_load + v_fma(v,s,v)
            a1 = fmaf(crow[e + 1], xr[e >> 2].y, a1);
            a2 = fmaf(crow[e + 2], xr[e >> 2].z, a2);
            a3 = fmaf(crow[e + 3], xr[e >> 2].w, a3);
        }
        crow += NE;
        float dist = bsqw[k] - ((a0 + a1) + (a2 + a3));
        if (dist < best) { best = dist; bestk = w * 128 + k; }  // strict <: first idx wins
    }
    s_best[w][lane] = best;
    s_idx[w][lane]  = bestk;
    __syncthreads();

    // phase c: per-b reduce over the 8 ascending k-eighths (strict < keeps earliest)
    if (t < 64) {
        float bv = s_best[0][t];
        int   bk = s_idx[0][t];
#pragma unroll
        for (int j = 1; j < 8; ++j) {
            float ob = s_best[j][t];
            if (ob < bv) { bv = ob; bk = s_idx[j][t]; }
        }
        s_kf[t] = bk;
        atomicAdd(&s_cnt[bk], 1);    // LDS histogram
    }
    __syncthreads();

    // phase d: one-hot rows. Wave w owns rows w*8..w*8+7; 4KB contiguous per row.
    for (int rr = 0; rr < 8; ++rr) {
        int r  = w * 8 + rr;
        int kk = s_kf[r];
        float* orow = oh + (size_t)(bq * 64 + r) * (ND * NK) + d * NK;
#pragma unroll
        for (int j = 0; j < 4; ++j) {
            int k0 = j * 256 + lane * 4;
            float4 o;
            o.x = (k0     == kk) ? 1.f : 0.f;
            o.y = (k0 + 1 == kk) ? 1.f : 0.f;
            o.z = (k0 + 2 == kk) ? 1.f : 0.f;
            o.w = (k0 + 3 == kk) ? 1.f : 0.f;
            *(float4*)(orow + k0) = o;
        }
    }

    // phase e+f: cw rows (exact reference arithmetic x+(c-x)) + scatter into ncb
    for (int rr = 0; rr < 8; ++rr) {
        int r  = w * 8 + rr;
        int kk = s_kf[r];
        int br = bq * 64 + r;
        float xv = x[(size_t)br * (ND * NE) + d * NE + lane];
        float cv = cbd[(size_t)kk * NE + lane];
        cw[(size_t)br * (ND * NE) + d * NE + lane] = xv + (cv - xv);
        float scale = GAINF / (ema[d * NK + kk] + EPSF);
        atomicAdd(&ncb[(size_t)d * (NK * NE) + (size_t)kk * NE + lane], scale * xv);
    }

    // phase g: flush histogram into nema (<= 8 blocks collide per bin)
    for (int kk = t; kk < NK; kk += 512) {
        int c = s_cnt[kk];
        if (c) atomicAdd(&nema[d * NK + kk], GAINF * (float)c);
    }
}

extern "C" void kernel_launch(void* const* d_in, const int* in_sizes, int n_in,
                              void* d_out, int out_size, void* d_ws, size_t ws_size,
                              hipStream_t stream) {
    const float* x   = (const float*)d_in[0];   // [512,4096]
    const float* cb  = (const float*)d_in[1];   // [64,1024,64]
    const float* ema = (const float*)d_in[2];   // [64,1024]
    (void)d_ws; (void)ws_size;

    float* out  = (float*)d_out;
    float* cw   = out;                          // 2,097,152
    float* oh   = out + 2097152;                // 33,554,432
    float* ncb  = out + 2097152 + 33554432;     // 4,194,304
    float* nema = ncb + 4194304;                // 65,536

    k_pre<<<4160, 256, 0, stream>>>(cb, ema, ncb, nema);

    dim3 g_fused(64, 8);                        // d on x -> XCD-aligned codebook reuse
    k_fused<<<g_fused, 512, 0, stream>>>(x, cb, ema, cw, oh, ncb, nema);
}